// Round 3
// baseline (7131.675 us; speedup 1.0000x reference)
//
#include <hip/hip_runtime.h>
#include <hip/hip_bf16.h>
#include <hip/hip_cooperative_groups.h>

namespace cg = cooperative_groups;

// Seq2Seq: B=64 S=64 T=32 E=512 U=1024 VE=16000 VD=32000
// fp32 in/out; internal GEMMs bf16 MFMA.
// R3: (a) persistent cooperative scan kernel (96 steps, grid.sync between
//     steps, c in registers, XCD-local Whh); (b) logits GEMM rebuilt on the
//     m97 structure: 128x128 tile, BK=32, global_load_lds width-16 staging.

typedef __hip_bfloat16 bf16;
typedef __bf16 bf16x8 __attribute__((ext_vector_type(8)));
typedef __bf16 bf16x4 __attribute__((ext_vector_type(4)));
typedef float f32x4 __attribute__((ext_vector_type(4)));

#define B_ 64
#define S_ 64
#define T_ 32
#define E_ 512
#define U_ 1024
#define VD_ 32000

__device__ __forceinline__ float sigf(float x) { return 1.0f / (1.0f + __expf(-x)); }

__device__ __forceinline__ bf16x8 frag_from_f32(const float* __restrict__ p) {
    float4 a = *(const float4*)p;
    float4 b = *(const float4*)(p + 4);
    bf16x8 r;
    r[0] = (__bf16)a.x; r[1] = (__bf16)a.y; r[2] = (__bf16)a.z; r[3] = (__bf16)a.w;
    r[4] = (__bf16)b.x; r[5] = (__bf16)b.y; r[6] = (__bf16)b.z; r[7] = (__bf16)b.w;
    return r;
}

// global -> LDS async copy, 16 B per lane (HW: wave-uniform LDS base + lane*16;
// our per-lane lds ptr equals base + lane*16 by construction).
__device__ __forceinline__ void gload_lds16(const __bf16* g, __bf16* l) {
    __builtin_amdgcn_global_load_lds(
        (const __attribute__((address_space(1))) void*)g,
        (__attribute__((address_space(3))) void*)l, 16, 0, 0);
}

// ---------------------------------------------------------------------------
// Generic C = A(M x K, optional row-gather) @ W(N x K)^T [+bias], fp32 C.
// W is bf16. One wave: 16-row M tile x NT 16-col N tiles. block=256 (4 waves).
// grid = (N/(64*NT), M/16). Used for input projections and the Q projection.
// ---------------------------------------------------------------------------
template <int NT, int AF32>
__global__ __launch_bounds__(256) void gemm_bt(
    const void* __restrict__ A, int lda, const int* __restrict__ aidx,
    const bf16* __restrict__ W, int K, const float* __restrict__ bias,
    float* __restrict__ Cout, int N)
{
    const int wave = threadIdx.x >> 6;
    const int lane = threadIdx.x & 63;
    const int quad = lane >> 4;
    const int mn   = lane & 15;

    const int mt  = blockIdx.y;
    const int nt0 = (blockIdx.x * 4 + wave) * NT;

    const int m = mt * 16 + mn;
    const long arow = aidx ? (long)aidx[m] : (long)m;
    const long aoff = arow * (long)lda + quad * 8;
    const long woff = (long)(nt0 * 16 + mn) * K + quad * 8;

    f32x4 acc[NT];
#pragma unroll
    for (int i = 0; i < NT; i++) acc[i] = (f32x4){0.f, 0.f, 0.f, 0.f};

    for (int k0 = 0; k0 < K; k0 += 32) {
        bf16x8 af;
        if (AF32) af = frag_from_f32((const float*)A + aoff + k0);
        else      af = *(const bf16x8*)((const __bf16*)A + aoff + k0);
#pragma unroll
        for (int i = 0; i < NT; i++) {
            bf16x8 wf = *(const bf16x8*)((const __bf16*)W + woff + (long)i * 16 * K + k0);
            acc[i] = __builtin_amdgcn_mfma_f32_16x16x32_bf16(af, wf, acc[i], 0, 0, 0);
        }
    }

    const int row0 = mt * 16 + quad * 4;
#pragma unroll
    for (int i = 0; i < NT; i++) {
        const int n = (nt0 + i) * 16 + mn;
        const float bv = bias ? bias[n] : 0.0f;
#pragma unroll
        for (int r = 0; r < 4; r++)
            Cout[(long)(row0 + r) * N + n] = acc[i][r] + bv;
    }
}

// ---------------------------------------------------------------------------
// Logits GEMM, m97 structure: out[b][n][t] = hc(2048x2048 bf16) @ Wd_b^T + bd.
// BM=BN=128, BK=32, 256 threads = 4 waves in 2x2 (each wave 64x64 = 4x4 MFMA).
// LDS single-buffered, 2 barriers/K-step, global_load_lds dwordx4 staging.
// grid = 4000 blocks 1D; XCD-chunk swizzle groups the 16 M-blocks of one
// N-chunk on one XCD so the W panel is fetched from HBM ~once.
// ---------------------------------------------------------------------------
__global__ __launch_bounds__(256) void logits_lds_kernel(
    const bf16* __restrict__ Abf,       // hc_all [2048][2048]
    const bf16* __restrict__ Wbf,       // Wd bf16 [32000][2048]
    const float* __restrict__ bias,
    float* __restrict__ out)
{
    __shared__ __bf16 As[128 * 32];
    __shared__ __bf16 Ws[128 * 32];

    const int tid  = threadIdx.x;
    const int lane = tid & 63;
    const int wave = tid >> 6;
    const int quad = lane >> 4, mn = lane & 15;
    const int wm = wave >> 1, wn = wave & 1;

    const int bid = blockIdx.x;                       // 0..3999
    const int nid = (bid & 7) * 500 + (bid >> 3);     // XCD-chunked
    const int mtb = nid & 15;                         // 16 M-blocks of 128
    const int ntb = nid >> 4;                         // 250 N-blocks of 128
    const long m0 = (long)mtb * 128, n0 = (long)ntb * 128;

    const __bf16* A = (const __bf16*)Abf;
    const __bf16* W = (const __bf16*)Wbf;

    // staging: chunk c in [0,512): row = c>>2, 16B col-block = c&3
    const int c0 = tid, c1 = tid + 256;
    const __bf16* ag0 = A + (m0 + (c0 >> 2)) * 2048 + (c0 & 3) * 8;
    const __bf16* ag1 = A + (m0 + (c1 >> 2)) * 2048 + (c1 & 3) * 8;
    const __bf16* wg0 = W + (n0 + (c0 >> 2)) * 2048 + (c0 & 3) * 8;
    const __bf16* wg1 = W + (n0 + (c1 >> 2)) * 2048 + (c1 & 3) * 8;
    __bf16* asl0 = As + c0 * 8;
    __bf16* asl1 = As + c1 * 8;
    __bf16* wsl0 = Ws + c0 * 8;
    __bf16* wsl1 = Ws + c1 * 8;

    const int arow = wm * 64 + mn;   // + mi*16
    const int wrow = wn * 64 + mn;   // + ni*16

    f32x4 acc[4][4];
#pragma unroll
    for (int mi = 0; mi < 4; mi++)
#pragma unroll
        for (int ni = 0; ni < 4; ni++) acc[mi][ni] = (f32x4){0.f, 0.f, 0.f, 0.f};

    for (int k0 = 0; k0 < 2048; k0 += 32) {
        __syncthreads();                 // previous tile's frag reads done
        gload_lds16(ag0 + k0, asl0);
        gload_lds16(ag1 + k0, asl1);
        gload_lds16(wg0 + k0, wsl0);
        gload_lds16(wg1 + k0, wsl1);
        __syncthreads();                 // compiler drains vmcnt before barrier

        bf16x8 a[4], w[4];
#pragma unroll
        for (int i = 0; i < 4; i++) {
            a[i] = *(const bf16x8*)(As + (arow + i * 16) * 32 + quad * 8);
            w[i] = *(const bf16x8*)(Ws + (wrow + i * 16) * 32 + quad * 8);
        }
#pragma unroll
        for (int mi = 0; mi < 4; mi++)
#pragma unroll
            for (int ni = 0; ni < 4; ni++)
                acc[mi][ni] = __builtin_amdgcn_mfma_f32_16x16x32_bf16(a[mi], w[ni], acc[mi][ni], 0, 0, 0);
    }

#pragma unroll
    for (int ni = 0; ni < 4; ni++) {
        const long n = n0 + wn * 64 + ni * 16 + mn;
        const float bv = bias[n];
#pragma unroll
        for (int mi = 0; mi < 4; mi++) {
            const long mrow0 = m0 + wm * 64 + mi * 16 + quad * 4;
#pragma unroll
            for (int r = 0; r < 4; r++) {
                const long mrow = mrow0 + r;
                const long b = mrow >> 5, t = mrow & 31;   // T_ = 32
                out[(b * VD_ + n) * T_ + t] = acc[mi][ni][r] + bv;
            }
        }
    }
}

// fp32-Wd fallback (no workspace for bf16 Wd): R2 direct kernel.
__global__ __launch_bounds__(256) void logits_direct_kernel(
    const bf16* __restrict__ A, const float* __restrict__ W,
    const float* __restrict__ bias, float* __restrict__ out)
{
    const int K = 2 * U_;
    const int wave = threadIdx.x >> 6, lane = threadIdx.x & 63;
    const int quad = lane >> 4, mn = lane & 15;
    const int bid = blockIdx.y * gridDim.x + blockIdx.x;
    const int nid = (bid & 7) * 500 + (bid >> 3);
    const int mtb = nid & 31, ntb = nid >> 5;
    const int m0 = mtb * 64, n0 = ntb * 256 + wave * 64;

    long aoff[4], woff[4];
#pragma unroll
    for (int m = 0; m < 4; m++) aoff[m] = (long)(m0 + m * 16 + mn) * K + quad * 8;
#pragma unroll
    for (int i = 0; i < 4; i++) woff[i] = (long)(n0 + i * 16 + mn) * K + quad * 8;

    f32x4 acc[4][4];
#pragma unroll
    for (int m = 0; m < 4; m++)
#pragma unroll
        for (int i = 0; i < 4; i++) acc[m][i] = (f32x4){0.f, 0.f, 0.f, 0.f};

#pragma unroll 2
    for (int k0 = 0; k0 < K; k0 += 32) {
        bf16x8 a[4];
#pragma unroll
        for (int m = 0; m < 4; m++)
            a[m] = *(const bf16x8*)((const __bf16*)A + aoff[m] + k0);
#pragma unroll
        for (int i = 0; i < 4; i++) {
            bf16x8 wf = frag_from_f32(W + woff[i] + k0);
#pragma unroll
            for (int m = 0; m < 4; m++)
                acc[m][i] = __builtin_amdgcn_mfma_f32_16x16x32_bf16(a[m], wf, acc[m][i], 0, 0, 0);
        }
    }
#pragma unroll
    for (int i = 0; i < 4; i++) {
        const int n = n0 + i * 16 + mn;
        const float bv = bias[n];
#pragma unroll
        for (int m = 0; m < 4; m++) {
            const int row0 = m0 + m * 16 + quad * 4;
#pragma unroll
            for (int r = 0; r < 4; r++) {
                const int mrow = row0 + r;
                const int b = mrow >> 5, t = mrow & 31;
                out[((long)b * VD_ + n) * T_ + t] = acc[m][i][r] + bv;
            }
        }
    }
}

// fp32 -> bf16 bulk convert (n multiple of 4).
__global__ __launch_bounds__(256) void cvt_kernel(
    const float* __restrict__ src, bf16* __restrict__ dst, int n)
{
    const int i = (blockIdx.x * 256 + threadIdx.x) * 4;
    if (i < n) {
        float4 v = *(const float4*)(src + i);
        dst[i + 0] = __float2bfloat16(v.x);
        dst[i + 1] = __float2bfloat16(v.y);
        dst[i + 2] = __float2bfloat16(v.z);
        dst[i + 3] = __float2bfloat16(v.w);
    }
}

// ---------------------------------------------------------------------------
// Persistent cooperative scan: all 64 encoder + 32 decoder LSTM steps.
// grid = 256 blocks (1/CU), block = 256 (4 waves: 1 gate each).
// Block <-> (b-tile, u-tile) mapping fixed across steps -> c stays in a
// register. h exchanged via global (o_enc / hc_all slots) + grid.sync().
// XCD-contiguous u-tiles: per-XCD Whh working set = 1 MB (L2-resident).
// ---------------------------------------------------------------------------
__global__ __launch_bounds__(256, 1) void scan_kernel(
    bf16* __restrict__ o_enc,           // [B][S][U]
    bf16* __restrict__ hc_all,          // [B][T][2U]
    const bf16* __restrict__ Whh_e, const bf16* __restrict__ Whh_d,
    const float* __restrict__ zx_enc, const float* __restrict__ zx_dec,
    const float* __restrict__ b_ih_e, const float* __restrict__ b_hh_e,
    const float* __restrict__ b_ih_d, const float* __restrict__ b_hh_d)
{
    cg::grid_group grid = cg::this_grid();
    __shared__ float zbuf[4][16][17];

    const int tid = threadIdx.x;
    const int g = tid >> 6, lane = tid & 63;
    const int quad = lane >> 4, mn = lane & 15;

    const int bid = blockIdx.x;
    const int idx = bid >> 3;
    const int ut = (bid & 7) * 8 + (idx & 7);   // 0..63 (XCD-contiguous)
    const int bt = idx >> 3;                    // 0..3
    const int u0 = ut * 16, b0 = bt * 16;

    // epilogue thread coords: one (b,u) per thread, fixed for whole kernel
    const int bl = tid >> 4, uc = tid & 15;
    const int bb = b0 + bl, ue = u0 + uc;

    float be[4], bdd[4];
#pragma unroll
    for (int k = 0; k < 4; k++) {
        be[k]  = b_ih_e[k * U_ + ue] + b_hh_e[k * U_ + ue];
        bdd[k] = b_ih_d[k * U_ + ue] + b_hh_d[k * U_ + ue];
    }
    float creg = 0.0f;

    const long woff = (long)(g * U_ + u0 + mn) * U_ + quad * 8;
    const __bf16* wpE = (const __bf16*)Whh_e;
    const __bf16* wpD = (const __bf16*)Whh_d;

    // ---- encoder ----
    for (int t = 0; t < S_; t++) {
        f32x4 acc = (f32x4){0.f, 0.f, 0.f, 0.f};
        if (t > 0) {
            const __bf16* hp = (const __bf16*)o_enc + (long)(t - 1) * U_;
            const long aoff = (long)(b0 + mn) * ((long)S_ * U_) + quad * 8;
#pragma unroll 8
            for (int k0 = 0; k0 < U_; k0 += 32) {
                bf16x8 af = *(const bf16x8*)(hp + aoff + k0);
                bf16x8 wf = *(const bf16x8*)(wpE + woff + k0);
                acc = __builtin_amdgcn_mfma_f32_16x16x32_bf16(af, wf, acc, 0, 0, 0);
            }
        }
#pragma unroll
        for (int r = 0; r < 4; r++) zbuf[g][quad * 4 + r][mn] = acc[r];
        __syncthreads();
        {
            const float* zxr = zx_enc + (long)bb * ((long)S_ * 4 * U_) + (long)t * 4 * U_;
            const float zi = zbuf[0][bl][uc] + zxr[ue]           + be[0];
            const float zf = zbuf[1][bl][uc] + zxr[U_ + ue]      + be[1];
            const float zg = zbuf[2][bl][uc] + zxr[2 * U_ + ue]  + be[2];
            const float zo = zbuf[3][bl][uc] + zxr[3 * U_ + ue]  + be[3];
            creg = sigf(zf) * creg + sigf(zi) * tanhf(zg);
            const float hv = sigf(zo) * tanhf(creg);
            o_enc[(long)bb * ((long)S_ * U_) + (long)t * U_ + ue] = __float2bfloat16(hv);
        }
        __threadfence();
        grid.sync();
    }

    // ---- decoder ----
    for (int t = 0; t < T_; t++) {
        const __bf16* hp;
        long hlda;
        if (t == 0) { hp = (const __bf16*)o_enc + (long)(S_ - 1) * U_; hlda = (long)S_ * U_; }
        else        { hp = (const __bf16*)hc_all + (long)(t - 1) * 2 * U_ + U_; hlda = (long)T_ * 2 * U_; }
        const long aoff = (long)(b0 + mn) * hlda + quad * 8;
        f32x4 acc = (f32x4){0.f, 0.f, 0.f, 0.f};
#pragma unroll 8
        for (int k0 = 0; k0 < U_; k0 += 32) {
            bf16x8 af = *(const bf16x8*)(hp + aoff + k0);
            bf16x8 wf = *(const bf16x8*)(wpD + woff + k0);
            acc = __builtin_amdgcn_mfma_f32_16x16x32_bf16(af, wf, acc, 0, 0, 0);
        }
#pragma unroll
        for (int r = 0; r < 4; r++) zbuf[g][quad * 4 + r][mn] = acc[r];
        __syncthreads();
        {
            const float* zxr = zx_dec + (long)bb * ((long)T_ * 4 * U_) + (long)t * 4 * U_;
            const float zi = zbuf[0][bl][uc] + zxr[ue]           + bdd[0];
            const float zf = zbuf[1][bl][uc] + zxr[U_ + ue]      + bdd[1];
            const float zg = zbuf[2][bl][uc] + zxr[2 * U_ + ue]  + bdd[2];
            const float zo = zbuf[3][bl][uc] + zxr[3 * U_ + ue]  + bdd[3];
            creg = sigf(zf) * creg + sigf(zi) * tanhf(zg);
            const float hv = sigf(zo) * tanhf(creg);
            hc_all[(long)bb * ((long)T_ * 2 * U_) + (long)t * 2 * U_ + U_ + ue] = __float2bfloat16(hv);
        }
        __threadfence();
        grid.sync();
    }
}

// ---------------------------------------------------------------------------
// Batched attention for ALL decoder steps (off critical path).
// grid = B*T = 2048 blocks, block = 256.
// ---------------------------------------------------------------------------
__global__ __launch_bounds__(256) void attn_all_kernel(
    const float* __restrict__ q,       // [B*T][U]
    const bf16* __restrict__ o_enc,    // [B][S][U]
    bf16* __restrict__ hc_all)         // [B][T][2U]
{
    const int bt = blockIdx.x;
    const int b = bt >> 5;             // T_ = 32
    __shared__ float sw[S_];
    const int tid = threadIdx.x, wave = tid >> 6, lane = tid & 63;
    const float* qb = q + (long)bt * U_;
    const bf16* ob = o_enc + (long)b * S_ * U_;

    const float4 q0 = *(const float4*)(qb + lane * 16 + 0);
    const float4 q1 = *(const float4*)(qb + lane * 16 + 4);
    const float4 q2 = *(const float4*)(qb + lane * 16 + 8);
    const float4 q3 = *(const float4*)(qb + lane * 16 + 12);
    for (int j = 0; j < 16; j++) {
        const int s = wave * 16 + j;
        const __bf16* orow = (const __bf16*)(ob + (long)s * U_);
        bf16x8 v0 = *(const bf16x8*)(orow + lane * 16);
        bf16x8 v1 = *(const bf16x8*)(orow + lane * 16 + 8);
        float acc = q0.x * (float)v0[0] + q0.y * (float)v0[1]
                  + q0.z * (float)v0[2] + q0.w * (float)v0[3]
                  + q1.x * (float)v0[4] + q1.y * (float)v0[5]
                  + q1.z * (float)v0[6] + q1.w * (float)v0[7]
                  + q2.x * (float)v1[0] + q2.y * (float)v1[1]
                  + q2.z * (float)v1[2] + q2.w * (float)v1[3]
                  + q3.x * (float)v1[4] + q3.y * (float)v1[5]
                  + q3.z * (float)v1[6] + q3.w * (float)v1[7];
        for (int off = 32; off; off >>= 1) acc += __shfl_down(acc, off);
        if (lane == 0) sw[s] = acc;
    }
    __syncthreads();
    if (wave == 0) {
        float v = sw[lane];
        float mx = v;
        for (int off = 32; off; off >>= 1) mx = fmaxf(mx, __shfl_xor(mx, off));
        const float e = __expf(v - mx);
        float sum = e;
        for (int off = 32; off; off >>= 1) sum += __shfl_xor(sum, off);
        sw[lane] = e / sum;
    }
    __syncthreads();
    const int u = tid * 4;
    float a0 = 0.f, a1 = 0.f, a2 = 0.f, a3 = 0.f;
    for (int s = 0; s < S_; s++) {
        const float w = sw[s];
        bf16x4 v = *(const bf16x4*)((const __bf16*)ob + (long)s * U_ + u);
        a0 += w * (float)v[0];
        a1 += w * (float)v[1];
        a2 += w * (float)v[2];
        a3 += w * (float)v[3];
    }
    bf16* outp = hc_all + (long)bt * 2 * U_ + u;
    outp[0] = __float2bfloat16(a0);
    outp[1] = __float2bfloat16(a1);
    outp[2] = __float2bfloat16(a2);
    outp[3] = __float2bfloat16(a3);
}

__global__ void build_idx(const int* __restrict__ y, int* __restrict__ idx)
{
    const int i = blockIdx.x * 256 + threadIdx.x;
    if (i < B_ * T_) {
        const int b = i >> 5, t = i & 31;
        idx[i] = y[b * (T_ + 1) + t];
    }
}

extern "C" void kernel_launch(void* const* d_in, const int* in_sizes, int n_in,
                              void* d_out, int out_size, void* d_ws, size_t ws_size,
                              hipStream_t stream)
{
    const int*   x       = (const int*)d_in[0];
    const int*   y       = (const int*)d_in[1];
    const float* enc_emb = (const float*)d_in[2];
    const float* dec_emb = (const float*)d_in[3];
    const float* W_ih_e  = (const float*)d_in[4];
    const float* W_hh_e  = (const float*)d_in[5];
    const float* b_ih_e  = (const float*)d_in[6];
    const float* b_hh_e  = (const float*)d_in[7];
    const float* Wa      = (const float*)d_in[8];
    const float* ba      = (const float*)d_in[9];
    const float* W_ih_d  = (const float*)d_in[10];
    const float* W_hh_d  = (const float*)d_in[11];
    const float* b_ih_d  = (const float*)d_in[12];
    const float* b_hh_d  = (const float*)d_in[13];
    const float* Wd      = (const float*)d_in[14];
    const float* bd      = (const float*)d_in[15];

    char* p = (char*)d_ws;
    auto alloc = [&](size_t bytes) { void* r = p; p += (bytes + 255) & ~255ull; return r; };
    float* zx_enc  = (float*)alloc((size_t)B_ * S_ * 4 * U_ * 4);   // 67 MB
    float* zx_dec  = (float*)alloc((size_t)B_ * T_ * 4 * U_ * 4);   // 34 MB
    bf16*  o_enc   = (bf16*)alloc((size_t)B_ * S_ * U_ * 2);        // 8.4 MB
    float* qbuf    = (float*)alloc((size_t)B_ * T_ * U_ * 4);       // 8.4 MB
    bf16*  hc_all  = (bf16*)alloc((size_t)B_ * T_ * 2 * U_ * 2);    // 8.4 MB
    bf16*  Whh_e_b = (bf16*)alloc((size_t)4 * U_ * U_ * 2);         // 8.4 MB
    bf16*  Whh_d_b = (bf16*)alloc((size_t)4 * U_ * U_ * 2);         // 8.4 MB
    bf16*  Wa_b    = (bf16*)alloc((size_t)U_ * U_ * 2);             // 2.1 MB
    bf16*  Wih_e_b = (bf16*)alloc((size_t)4 * U_ * E_ * 2);         // 4.2 MB
    bf16*  Wih_d_b = (bf16*)alloc((size_t)4 * U_ * E_ * 2);         // 4.2 MB
    int*   dec_idx = (int*)alloc((size_t)B_ * T_ * 4);

    // Wd bf16 copy (131 MB) only if workspace allows; else fp32 fallback.
    const size_t wd_bytes = (size_t)VD_ * 2 * U_ * 2;
    bf16* Wd_b = nullptr;
    if (ws_size >= (size_t)(p - (char*)d_ws) + wd_bytes + 256)
        Wd_b = (bf16*)alloc(wd_bytes);

    build_idx<<<8, 256, 0, stream>>>(y, dec_idx);

    // Weights -> bf16 once per launch.
    cvt_kernel<<<(4 * U_ * U_) / 1024, 256, 0, stream>>>(W_hh_e, Whh_e_b, 4 * U_ * U_);
    cvt_kernel<<<(4 * U_ * U_) / 1024, 256, 0, stream>>>(W_hh_d, Whh_d_b, 4 * U_ * U_);
    cvt_kernel<<<(U_ * U_) / 1024, 256, 0, stream>>>(Wa, Wa_b, U_ * U_);
    cvt_kernel<<<(4 * U_ * E_) / 1024, 256, 0, stream>>>(W_ih_e, Wih_e_b, 4 * U_ * E_);
    cvt_kernel<<<(4 * U_ * E_) / 1024, 256, 0, stream>>>(W_ih_d, Wih_d_b, 4 * U_ * E_);
    if (Wd_b)
        cvt_kernel<<<(VD_ * 2 * U_) / 1024, 256, 0, stream>>>(Wd, Wd_b, VD_ * 2 * U_);

    // Input projections (biases folded into scan epilogue). A: fp32 gather.
    gemm_bt<4, 1><<<dim3((4 * U_) / 256, (B_ * S_) / 16), 256, 0, stream>>>(
        enc_emb, E_, x, Wih_e_b, E_, nullptr, zx_enc, 4 * U_);
    gemm_bt<4, 1><<<dim3((4 * U_) / 256, (B_ * T_) / 16), 256, 0, stream>>>(
        dec_emb, E_, dec_idx, Wih_d_b, E_, nullptr, zx_dec, 4 * U_);

    // Persistent cooperative scan: all 96 LSTM steps in one launch.
    {
        void* sargs[] = {
            (void*)&o_enc, (void*)&hc_all, (void*)&Whh_e_b, (void*)&Whh_d_b,
            (void*)&zx_enc, (void*)&zx_dec, (void*)&b_ih_e, (void*)&b_hh_e,
            (void*)&b_ih_d, (void*)&b_hh_d };
        hipLaunchCooperativeKernel((void*)scan_kernel, dim3(256), dim3(256),
                                   sargs, 0, stream);
    }

    // Q for all decoder steps: (B*T x U) = H_dec @ Wa^T + ba.
    gemm_bt<4, 0><<<dim3(U_ / 256, (B_ * T_) / 16), 256, 0, stream>>>(
        hc_all + U_, 2 * U_, nullptr, Wa_b, U_, ba, qbuf, U_);

    // Batched attention: ctx for all (b,t) -> hc_all first half.
    attn_all_kernel<<<B_ * T_, 256, 0, stream>>>(qbuf, o_enc, hc_all);

    // Logits.
    if (Wd_b)
        logits_lds_kernel<<<4000, 256, 0, stream>>>(hc_all, Wd_b, bd, (float*)d_out);
    else
        logits_direct_kernel<<<dim3(32, 125), 256, 0, stream>>>(hc_all, Wd, bd, (float*)d_out);
}